// Round 8
// baseline (392.641 us; speedup 1.0000x reference)
//
#include <hip/hip_runtime.h>
#include <math.h>

#define D      128
#define S_LEN  64
#define B_SZ   512
#define NH     4
#define DH     32
#define NB     2
#define VOCAB  9
#define EPS    1e-5f
#define NTOK   (B_SZ * S_LEN)

// ---------------- DPP helpers (ctrl must be compile-time constant) ----------
template <int CTRL>
__device__ __forceinline__ float dppf(float x) {
    return __int_as_float(__builtin_amdgcn_update_dpp(
        0, __float_as_int(x), CTRL, 0xF, 0xF, true));
}
// wave64 sum -> wave-uniform scalar (canonical row_shr/bcast sequence)
__device__ __forceinline__ float wsum64(float x) {
    x += dppf<0x111>(x);  // row_shr:1
    x += dppf<0x112>(x);  // row_shr:2
    x += dppf<0x114>(x);  // row_shr:4
    x += dppf<0x118>(x);  // row_shr:8
    x += dppf<0x142>(x);  // row_bcast:15
    x += dppf<0x143>(x);  // row_bcast:31
    return __int_as_float(__builtin_amdgcn_readlane(__float_as_int(x), 63));
}

// LDS swizzles (all xor bits>=2 -> float4 alignment preserved)
__device__ __forceinline__ int xc3(int t, int c) { return c ^ (((t >> 1) & 7) << 2); }
__device__ __forceinline__ int xa (int t, int c) { return c ^ ((t & 7) << 2); }
__device__ __forceinline__ int xg (int c)        { return c ^ ((c >> 5) << 3); }

// ---------------------------------------------------------------------------
// Kernel 1: h = emb[x]; LN1 stats (mu, rstd). One wave per token.
// ---------------------------------------------------------------------------
__global__ __launch_bounds__(256) void k_embed(const int* __restrict__ x,
                                               const float* __restrict__ emb,
                                               float* __restrict__ h,
                                               float* __restrict__ stats)
{
    int lane = threadIdx.x & 63;
    int wv   = threadIdx.x >> 6;
    int tok  = blockIdx.x * 4 + wv;
    int xi   = x[tok];
    float2 v = ((const float2*)(emb + xi * D))[lane];
    ((float2*)(h + (size_t)tok * D))[lane] = v;
    float s1 = wsum64(v.x + v.y);
    float s2 = wsum64(v.x * v.x + v.y * v.y);
    float mu  = s1 * (1.0f / D);
    float var = s2 * (1.0f / D) - mu * mu;
    if (lane == 0) {
        stats[tok * 2]     = mu;
        stats[tok * 2 + 1] = rsqrtf(var + EPS);
    }
}

// ---------------------------------------------------------------------------
// Kernel 1.5: gx = LN1(h) @ Wg + bias as a tiled GEMM.
// 32 tokens/block, 256 threads; whole Wg (64 KiB) staged once in LDS.
// ---------------------------------------------------------------------------
__global__ __launch_bounds__(256, 2) void k_gx(const float* __restrict__ Wg,    // (4,NH,DH,DH)
                                               const float* __restrict__ bias,  // (NH,4,DH)
                                               const float* __restrict__ lnw,   // (D)
                                               const float* __restrict__ h,     // (B*S, D)
                                               const float* __restrict__ stats, // (B*S, 2)
                                               float* __restrict__ gx)          // (B*NH*S, 128)
{
    __shared__ float xs[32 * 128];        // 16 KiB
    __shared__ float wl[4 * 32 * 128];    // 64 KiB  [n][k][gk'] swizzled

    int tid  = threadIdx.x;
    int lane = tid & 63;
    int wv   = tid >> 6;
    size_t tok0 = (size_t)blockIdx.x * 32;

    // ---- stage all Wg: wl[n][i][g*32+hh ^ sw] = Wg[g][n][hh][i] ----
    {
        int q = tid & 7;                   // float4 index along i
        #pragma unroll
        for (int it = 0; it < 16; ++it) {
            int row = it * 32 + (tid >> 3);        // 0..511 = (g*4+n)*32+hh
            int g  = row >> 7;
            int n  = (row >> 5) & 3;
            int hh = row & 31;
            float4 v = *(const float4*)(Wg + row * 32 + q * 4);
            int col = g * 32 + hh;
            int sw  = q << 2;
            float* dst = wl + n * 4096;
            dst[(q * 4 + 0) * 128 + (col ^ sw)] = v.x;
            dst[(q * 4 + 1) * 128 + (col ^ sw)] = v.y;
            dst[(q * 4 + 2) * 128 + (col ^ sw)] = v.z;
            dst[(q * 4 + 3) * 128 + (col ^ sw)] = v.w;
        }
    }
    // ---- stage xn (LN1 applied; stats precomputed) ----
    for (int i = 0; i < 8; ++i) {
        int t = wv * 8 + i;
        const float* hp = h + (tok0 + t) * D;
        float mu = stats[(tok0 + t) * 2];
        float rs = stats[(tok0 + t) * 2 + 1];
        float v1 = (hp[lane]      - mu) * rs * lnw[lane];
        float v2 = (hp[64 + lane] - mu) * rs * lnw[64 + lane];
        xs[t * 128 + xg(lane)]      = v1;
        xs[t * 128 + xg(lane + 64)] = v2;
    }
    __syncthreads();

    int nh   = lane >> 4;          // head
    int col0 = (lane & 15) * 8;    // 8 output cols within head
    int t0   = wv * 8;             // 8 tokens

    float acc[8][8];
    #pragma unroll
    for (int j = 0; j < 8; ++j)
        #pragma unroll
        for (int cc = 0; cc < 8; ++cc) acc[j][cc] = 0.f;

    const float* wbase = wl + nh * 4096;
    #pragma unroll 4
    for (int k = 0; k < 32; ++k) {
        int sw = (k >> 2) << 2;
        float4 w0 = *(const float4*)&wbase[k * 128 + (col0 ^ sw)];
        float4 w1 = *(const float4*)&wbase[k * 128 + ((col0 + 4) ^ sw)];
        int ac = (nh * 32 + k) ^ (nh << 3);
        #pragma unroll
        for (int j = 0; j < 8; ++j) {
            float a = xs[(t0 + j) * 128 + ac];
            acc[j][0] = fmaf(a, w0.x, acc[j][0]);
            acc[j][1] = fmaf(a, w0.y, acc[j][1]);
            acc[j][2] = fmaf(a, w0.z, acc[j][2]);
            acc[j][3] = fmaf(a, w0.w, acc[j][3]);
            acc[j][4] = fmaf(a, w1.x, acc[j][4]);
            acc[j][5] = fmaf(a, w1.y, acc[j][5]);
            acc[j][6] = fmaf(a, w1.z, acc[j][6]);
            acc[j][7] = fmaf(a, w1.w, acc[j][7]);
        }
    }

    float4 bb0 = *(const float4*)(bias + nh * 128 + col0);
    float4 bb1 = *(const float4*)(bias + nh * 128 + col0 + 4);
    #pragma unroll
    for (int j = 0; j < 8; ++j) {
        int gt = (int)tok0 + t0 + j;
        int bb = gt >> 6;
        int ss = gt & 63;
        float* op = gx + ((size_t)(bb * NH + nh) * S_LEN + ss) * 128 + col0;
        float4 o0v, o1v;
        o0v.x = acc[j][0] + bb0.x; o0v.y = acc[j][1] + bb0.y;
        o0v.z = acc[j][2] + bb0.z; o0v.w = acc[j][3] + bb0.w;
        o1v.x = acc[j][4] + bb1.x; o1v.y = acc[j][5] + bb1.y;
        o1v.z = acc[j][6] + bb1.z; o1v.w = acc[j][7] + bb1.w;
        *(float4*)op       = o0v;
        *(float4*)(op + 4) = o1v;
    }
}

// ---------------------------------------------------------------------------
// Kernel 2: slim sLSTM scan + groupnorm + residual, one wave per (b, head).
// R6/R7 post-mortem: compiler kept only 48 VGPRs and REMATERIALIZED the
// RA/RB loads inside the s-loop (legal under __restrict__), making every
// step latency-bound on lane-divergent buffer_loads. The empty asm with
// "+v" makes each weight an opaque VGPR def -> must stay resident.
// ---------------------------------------------------------------------------
__global__ __launch_bounds__(64, 1) void k_scan(const float* __restrict__ Rm,   // (NH,DH,4*DH)
                                                const float* __restrict__ gnw,  // (D)
                                                const float* __restrict__ gx,   // (B*NH*S, 128)
                                                float* __restrict__ h)          // (B*S, D) in/out
{
    int b    = blockIdx.x >> 2;
    int n    = blockIdx.x & 3;
    int lane = threadIdx.x;
    int e    = lane >> 1;
    int sub  = lane & 1;
    int colA = sub * DH + e;           // i (sub0) / f (sub1)

    float RA[DH], RB[DH];
    #pragma unroll
    for (int i = 0; i < DH; ++i) {
        RA[i] = Rm[(n * DH + i) * 128 + colA];
        RB[i] = Rm[(n * DH + i) * 128 + 64 + colA];   // z / o
    }
    // Pin weights in VGPRs: opaque def defeats load rematerialization.
    #pragma unroll
    for (int i = 0; i < DH; ++i) {
        asm("" : "+v"(RA[i]));
        asm("" : "+v"(RB[i]));
    }
    float gw = gnw[n * DH + e];

    float c = 0.f, nacc = 0.f, m = 0.f;
    float hu[DH];
    #pragma unroll
    for (int i = 0; i < DH; ++i) hu[i] = 0.f;

    float* hb = h + ((size_t)b * S_LEN) * D + n * DH;
    const float* gxp = gx + ((size_t)(b * NH + n) * S_LEN) * 128;

    float gA0 = gxp[colA],       gB0 = gxp[64 + colA];
    float gA1 = gxp[128 + colA], gB1 = gxp[192 + colA];
    float hr0 = hb[e];
    float hr1 = hb[D + e];

    for (int s = 0; s < S_LEN; ++s) {
        int sp = (s + 2 < S_LEN) ? s + 2 : s;
        float nGA = gxp[sp * 128 + colA];
        float nGB = gxp[sp * 128 + 64 + colA];
        float nhr = hb[sp * D + e];

        float r0=0,r1=0,r2=0,r3=0,q0=0,q1=0,q2=0,q3=0;
        #pragma unroll
        for (int i = 0; i < DH; i += 4) {
            r0 = fmaf(hu[i],   RA[i],   r0);
            r1 = fmaf(hu[i+1], RA[i+1], r1);
            r2 = fmaf(hu[i+2], RA[i+2], r2);
            r3 = fmaf(hu[i+3], RA[i+3], r3);
            q0 = fmaf(hu[i],   RB[i],   q0);
            q1 = fmaf(hu[i+1], RB[i+1], q1);
            q2 = fmaf(hu[i+2], RB[i+2], q2);
            q3 = fmaf(hu[i+3], RB[i+3], q3);
        }
        float rawA = gA0 + ((r0 + r1) + (r2 + r3));
        float rawB = gB0 + ((q0 + q1) + (q2 + q3));

        float xA = dppf<0xB1>(rawA);   // quad_perm [1,0,3,2] = xor1
        float xB = dppf<0xB1>(rawB);
        float i_r = sub ? xA   : rawA;
        float f_r = sub ? rawA : xA;
        float z_r = sub ? xB   : rawB;
        float o_r = sub ? rawB : xB;

        // log_sigmoid(f) = min(f,0) - ln(1+exp(-|f|)) via hw exp/log2
        float lsf  = fminf(f_r, 0.f)
                   - 0.69314718055994531f * __log2f(1.0f + __expf(-fabsf(f_r)));
        float lfm  = m + lsf;
        float mnew = fmaxf(i_r, lfm);
        float ig   = __expf(i_r - mnew);
        float fg   = __expf(lfm - mnew);
        float t    = __expf(2.f * z_r);
        float tz   = 1.f - 2.f / (t + 1.f);   // tanh, stable both ends
        c    = fg * c + ig * tz;
        nacc = fg * nacc + ig;
        m    = mnew;
        float hv = c / (nacc * (1.f + __expf(-o_r)));   // sigmoid(o)*c/n

        // groupnorm over DH (each element appears twice -> /64)
        float s1 = wsum64(hv);
        float s2 = wsum64(hv * hv);
        float mu  = s1 * (1.f / 64.f);
        float var = s2 * (1.f / 64.f) - mu * mu;
        float hn  = (hv - mu) * rsqrtf(var + EPS) * gw;

        if (!sub) hb[s * D + e] = hr0 + hn;   // residual write (h_mid)

        #pragma unroll
        for (int i = 0; i < DH; ++i)
            hu[i] = __int_as_float(
                __builtin_amdgcn_readlane(__float_as_int(hv), 2 * i));

        gA0 = gA1; gB0 = gB1; hr0 = hr1;
        gA1 = nGA; gB1 = nGB; hr1 = nhr;
    }
}

// ---------------------------------------------------------------------------
// Kernel 3: fused LN2 -> up GEMM -> GeLU -> down GEMM -> residual -> tail.
// 32 tokens/block, 256 threads, 40 KiB LDS.
// launch_bounds arg=2: empirically VGPR cap = 256/arg -> 128 (no spill);
// 128 VGPR + 40 KiB LDS still allows 4 blocks/CU.
// ---------------------------------------------------------------------------
template <int LAST>
__global__ __launch_bounds__(256, 2) void k_ff(float* __restrict__ h,
                                               const float* __restrict__ ln2w,
                                               const float* __restrict__ wup,    // (2D, D)
                                               const float* __restrict__ wdn,    // (D, D)
                                               float* __restrict__ stats_out,
                                               const float* __restrict__ lastw,
                                               const float* __restrict__ projw,
                                               const float* __restrict__ projb,
                                               float* __restrict__ out)
{
    __shared__ float xs[32 * 128];      // 16 KiB
    __shared__ float as_[32 * 64];      // 8 KiB
    __shared__ float wt[2 * 32 * 64];   // 16 KiB  [slot][k][o'] swizzled

    int tid  = threadIdx.x;
    int lane = tid & 63;
    int wv   = tid >> 6;
    size_t tok0 = (size_t)blockIdx.x * 32;

    // ---- phase 1: LN2 into xs ----
    for (int i = 0; i < 8; ++i) {
        int t = wv * 8 + i;
        const float* hp = h + (tok0 + t) * D;
        float v1 = hp[lane], v2 = hp[64 + lane];
        float s1 = wsum64(v1 + v2);
        float s2 = wsum64(v1 * v1 + v2 * v2);
        float mu = s1 * (1.0f / D);
        float rs = rsqrtf(s2 * (1.0f / D) - mu * mu + EPS);
        xs[t * D + xc3(t, lane)]      = (v1 - mu) * rs * ln2w[lane];
        xs[t * D + xc3(t, lane + 64)] = (v2 - mu) * rs * ln2w[64 + lane];
    }

    // staging constants: q = float4 idx along k, r0/r0+32 = output rows
    int q     = tid & 7;
    int r0    = tid >> 3;          // 0..31
    int goff0 = r0 * D + q * 4;
    int goff1 = (r0 + 32) * D + q * 4;
    int s0    = r0 ^ (q << 2);     // swizzled o-index for LDS store
    int kb    = q * 4;

    auto ffld = [&](int id, float4* pre) {
        int p = (id >= 6) ? 1 : 0;
        int j = id - p * 6;
        const float* b0;
        const float* b1;
        if (j < 4) { b0 = wup + (p * 64) * D + j * 32;
                     b1 = wup + (128 + p * 64) * D + j * 32; }
        else       { int jj = j - 4;
                     b0 = wdn + p * 64 + jj * 32;
                     b1 = wdn + 64 * D + p * 64 + jj * 32; }
        pre[0] = *(const float4*)(b0 + goff0);
        pre[1] = *(const float4*)(b0 + goff1);
        pre[2] = *(const float4*)(b1 + goff0);
        pre[3] = *(const float4*)(b1 + goff1);
    };
    auto fst = [&](const float4* pre) {
        #pragma unroll
        for (int cc = 0; cc < 4; ++cc) {
            const float* p0 = (const float*)&pre[0];
            const float* p1 = (const float*)&pre[1];
            const float* p2 = (const float*)&pre[2];
            const float* p3 = (const float*)&pre[3];
            wt[(kb + cc) * 64 + s0]           = p0[cc];
            wt[(kb + cc) * 64 + s0 + 32]      = p1[cc];
            wt[2048 + (kb + cc) * 64 + s0]      = p2[cc];
            wt[2048 + (kb + cc) * 64 + s0 + 32] = p3[cc];
        }
    };

    int ti = tid >> 4;    // 0..15
    int oi = tid & 15;    // 0..15
    int t0 = ti * 2;
    int o0 = oi * 4;

    float accd[2][2][4];
    #pragma unroll
    for (int a1 = 0; a1 < 2; ++a1)
        #pragma unroll
        for (int j = 0; j < 2; ++j)
            #pragma unroll
            for (int cc = 0; cc < 4; ++cc) accd[a1][j][cc] = 0.f;

    float4 pre[4];
    ffld(0, pre);
    int id = 1;

    #pragma unroll
    for (int p = 0; p < 2; ++p) {
        float accg[2][4], accv[2][4];
        #pragma unroll
        for (int j = 0; j < 2; ++j)
            #pragma unroll
            for (int cc = 0; cc < 4; ++cc) { accg[j][cc] = 0.f; accv[j][cc] = 0.f; }

        // ---- UP: 4 chunks of 32 k ----
        for (int c4 = 0; c4 < 4; ++c4) {
            __syncthreads();
            fst(pre);
            if (id < 12) ffld(id, pre);
            ++id;
            __syncthreads();
            int kc = c4 * 32;
            #pragma unroll
            for (int k4 = 0; k4 < 8; ++k4) {
                float4 a0 = *(const float4*)&xs[t0 * D + xc3(t0, kc + k4 * 4)];
                float4 a1v = *(const float4*)&xs[(t0 + 1) * D + xc3(t0 + 1, kc + k4 * 4)];
                int ws = k4 << 2;
                #pragma unroll
                for (int i = 0; i < 4; ++i) {
                    int k = k4 * 4 + i;
                    float4 bg = *(const float4*)&wt[k * 64 + (o0 ^ ws)];
                    float4 bv = *(const float4*)&wt[2048 + k * 64 + (o0 ^ ws)];
                    float ax0 = ((const float*)&a0)[i];
                    float ax1 = ((const float*)&a1v)[i];
                    accg[0][0] = fmaf(ax0, bg.x, accg[0][0]);
                    accg[0][1] = fmaf(ax0, bg.y, accg[0][1]);
                    accg[0][2] = fmaf(ax0, bg.z, accg[0][2]);
                    accg[0][3] = fmaf(ax0, bg.w, accg[0][3]);
                    accg[1][0] = fmaf(ax1, bg.x, accg[1][0]);
                    accg[1][1] = fmaf(ax1, bg.y, accg[1][1]);
                    accg[1][2] = fmaf(ax1, bg.z, accg[1][2]);
                    accg[1][3] = fmaf(ax1, bg.w, accg[1][3]);
                    accv[0][0] = fmaf(ax0, bv.x, accv[0][0]);
                    accv[0][1] = fmaf(ax0, bv.y, accv[0][1]);
                    accv[0][2] = fmaf(ax0, bv.z, accv[0][2]);
                    accv[0][3] = fmaf(ax0, bv.w, accv[0][3]);
                    accv[1][0] = fmaf(ax1, bv.x, accv[1][0]);
                    accv[1][1] = fmaf(ax1, bv.y, accv[1][1]);
                    accv[1][2] = fmaf(ax1, bv.z, accv[1][2]);
                    accv[1][3] = fmaf(ax1, bv.w, accv[1][3]);
                }
            }
        }
        // act = gelu_exact(gate) * val -> as_
        #pragma unroll
        for (int j = 0; j < 2; ++j) {
            int t = t0 + j;
            float4 av;
            float* ap = (float*)&av;
            #pragma unroll
            for (int cc = 0; cc < 4; ++cc) {
                float g = accg[j][cc];
                float u = accv[j][cc];
                ap[cc] = 0.5f * g * (1.0f + erff(g * 0.70710678118654752f)) * u;
            }
            *(float4*)&as_[t * 64 + xa(t, o0)] = av;
        }
        // ---- DOWN: 2 chunks of 32 k ----
        for (int c2 = 0; c2 < 2; ++c2) {
            __syncthreads();
            fst(pre);
            if (id < 12) ffld(id, pre);
            ++id;
            __syncthreads();
            int kc = c2 * 32;
            #pragma unroll
            for (int k4 = 0; k4 < 8; ++k4) {
                float4 a0 = *(const float4*)&as_[t0 * 64 + xa(t0, kc + k4 * 4)];
                float4 a1v = *(const float4*)&as_[(t0 + 1) * 64 + xa(t0 + 1, kc + k4 * 4)];
                int ws = k4 << 2;
                #pragma unroll
                for (int i = 0; i < 4; ++i) {
                    int k = k4 * 4 + i;
                    float4 b0v = *(const float4*)&wt[k * 64 + (o0 ^ ws)];
                    float4 b1v = *(const float4*)&wt[2048 + k * 64 + (o0 ^ ws)];
                    float ax0 = ((const float*)&a0)[i];
                    float ax1 = ((const float*)&a1v)[i];
                    accd[0][0][0] = fmaf(ax0, b0v.x, accd[0][0][0]);
                    accd[0][0][1] = fmaf(ax0, b0v.y, accd[0][0][1]);
                    accd[0][0][2] = fmaf(ax0, b0v.z, accd[0][0][2]);
                    accd[0][0][3] = fmaf(ax0, b0v.w, accd[0][0][3]);
                    accd[0][1][0] = fmaf(ax1, b0v.x, accd[0][1][0]);
                    accd[0][1][1] = fmaf(ax1, b0v.y, accd[0][1][1]);
                    accd[0][1][2] = fmaf(ax1, b0v.z, accd[0][1][2]);
                    accd[0][1][3] = fmaf(ax1, b0v.w, accd[0][1][3]);
                    accd[1][0][0] = fmaf(ax0, b1v.x, accd[1][0][0]);
                    accd[1][0][1] = fmaf(ax0, b1v.y, accd[1][0][1]);
                    accd[1][0][2] = fmaf(ax0, b1v.z, accd[1][0][2]);
                    accd[1][0][3] = fmaf(ax0, b1v.w, accd[1][0][3]);
                    accd[1][1][0] = fmaf(ax1, b1v.x, accd[1][1][0]);
                    accd[1][1][1] = fmaf(ax1, b1v.y, accd[1][1][1]);
                    accd[1][1][2] = fmaf(ax1, b1v.z, accd[1][1][2]);
                    accd[1][1][3] = fmaf(ax1, b1v.w, accd[1][1][3]);
                }
            }
        }
    }

    // ---- epilogue: residual add, stash hnew in xs ----
    #pragma unroll
    for (int j = 0; j < 2; ++j) {
        int t = t0 + j;
        size_t tok = tok0 + t;
        #pragma unroll
        for (int a1 = 0; a1 < 2; ++a1) {
            int cb = a1 * 64 + o0;
            float4 hres = *(const float4*)(h + tok * D + cb);
            float4 hn;
            hn.x = hres.x + accd[a1][j][0];
            hn.y = hres.y + accd[a1][j][1];
            hn.z = hres.z + accd[a1][j][2];
            hn.w = hres.w + accd[a1][j][3];
            if (!LAST) *(float4*)(h + tok * D + cb) = hn;
            *(float4*)&xs[t * D + xc3(t, cb)] = hn;
        }
    }
    __syncthreads();

    // ---- final per-token phase ----
    if (!LAST) {
        for (int i = 0; i < 8; ++i) {
            int t = wv * 8 + i;
            float v1 = xs[t * D + xc3(t, lane)];
            float v2 = xs[t * D + xc3(t, lane + 64)];
            float s1 = wsum64(v1 + v2);
            float s2 = wsum64(v1 * v1 + v2 * v2);
            float mu = s1 * (1.0f / D);
            float rs = rsqrtf(s2 * (1.0f / D) - mu * mu + EPS);
            if (lane == 0) {
                stats_out[(tok0 + t) * 2]     = mu;
                stats_out[(tok0 + t) * 2 + 1] = rs;
            }
        }
    } else {
        float pw1[VOCAB], pw2[VOCAB], pb[VOCAB];
        #pragma unroll
        for (int v = 0; v < VOCAB; ++v) {
            pw1[v] = projw[v * D + lane];
            pw2[v] = projw[v * D + 64 + lane];
            pb[v]  = projb[v];
        }
        for (int i = 0; i < 8; ++i) {
            int t = wv * 8 + i;
            float v1 = xs[t * D + xc3(t, lane)];
            float v2 = xs[t * D + xc3(t, lane + 64)];
            float s1 = wsum64(v1 + v2);
            float s2 = wsum64(v1 * v1 + v2 * v2);
            float mu = s1 * (1.0f / D);
            float rs = rsqrtf(s2 * (1.0f / D) - mu * mu + EPS);
            float x1 = (v1 - mu) * rs * lastw[lane];
            float x2 = (v2 - mu) * rs * lastw[64 + lane];
            #pragma unroll
            for (int v = 0; v < VOCAB; ++v) {
                float pp = wsum64(fmaf(x1, pw1[v], x2 * pw2[v]));
                if (lane == 0) out[(tok0 + t) * VOCAB + v] = pp + pb[v];
            }
        }
    }
}

// ---------------------------------------------------------------------------
extern "C" void kernel_launch(void* const* d_in, const int* in_sizes, int n_in,
                              void* d_out, int out_size, void* d_ws, size_t ws_size,
                              hipStream_t stream)
{
    const int*   x     = (const int*)  d_in[0];
    const float* emb   = (const float*)d_in[1];
    const float* ln1   = (const float*)d_in[2];
    const float* Wg    = (const float*)d_in[3];
    const float* Rm    = (const float*)d_in[4];
    const float* bias  = (const float*)d_in[5];
    const float* gnw   = (const float*)d_in[6];
    const float* ln2   = (const float*)d_in[7];
    const float* wup   = (const float*)d_in[8];
    const float* wdn   = (const float*)d_in[9];
    const float* postw = (const float*)d_in[10];
    const float* projw = (const float*)d_in[11];
    const float* projb = (const float*)d_in[12];
    float* out   = (float*)d_out;
    float* hbuf  = (float*)d_ws;                       // (B*S, D)
    float* stats = hbuf + (size_t)NTOK * D;            // (B*S, 2)
    float* gxbuf = stats + (size_t)NTOK * 2;           // (B*NH*S, 128)

    k_embed<<<NTOK / 4, 256, 0, stream>>>(x, emb, hbuf, stats);

    for (int bi = 0; bi < NB; ++bi) {
        k_gx<<<NTOK / 32, 256, 0, stream>>>(Wg + bi * 4 * NH * DH * DH,
                                            bias + bi * NH * 4 * DH,
                                            ln1 + bi * D,
                                            hbuf, stats, gxbuf);
        k_scan<<<B_SZ * NH, 64, 0, stream>>>(Rm + bi * NH * DH * 4 * DH,
                                             gnw + bi * D,
                                             gxbuf, hbuf);
        if (bi == 0)
            k_ff<0><<<NTOK / 32, 256, 0, stream>>>(hbuf, ln2 + bi * D,
                                                   wup + bi * 2 * D * D,
                                                   wdn + bi * D * D,
                                                   stats, nullptr, nullptr,
                                                   nullptr, nullptr);
        else
            k_ff<1><<<NTOK / 32, 256, 0, stream>>>(hbuf, ln2 + bi * D,
                                                   wup + bi * 2 * D * D,
                                                   wdn + bi * D * D,
                                                   nullptr, postw, projw,
                                                   projb, out);
    }
}

// Round 9
// 387.737 us; speedup vs baseline: 1.0126x; 1.0126x over previous
//
#include <hip/hip_runtime.h>
#include <math.h>

#define D      128
#define S_LEN  64
#define B_SZ   512
#define NH     4
#define DH     32
#define NB     2
#define VOCAB  9
#define EPS    1e-5f
#define NTOK   (B_SZ * S_LEN)

// ---------------- DPP helpers (ctrl must be compile-time constant) ----------
template <int CTRL>
__device__ __forceinline__ float dppf(float x) {
    return __int_as_float(__builtin_amdgcn_update_dpp(
        0, __float_as_int(x), CTRL, 0xF, 0xF, true));
}
// wave64 sum -> wave-uniform scalar (canonical row_shr/bcast sequence)
__device__ __forceinline__ float wsum64(float x) {
    x += dppf<0x111>(x);  // row_shr:1
    x += dppf<0x112>(x);  // row_shr:2
    x += dppf<0x114>(x);  // row_shr:4
    x += dppf<0x118>(x);  // row_shr:8
    x += dppf<0x142>(x);  // row_bcast:15
    x += dppf<0x143>(x);  // row_bcast:31
    return __int_as_float(__builtin_amdgcn_readlane(__float_as_int(x), 63));
}

// LDS swizzles (all xor bits>=2 -> float4 alignment preserved)
__device__ __forceinline__ int xc3(int t, int c) { return c ^ (((t >> 1) & 7) << 2); }
__device__ __forceinline__ int xa (int t, int c) { return c ^ ((t & 7) << 2); }
__device__ __forceinline__ int xg (int c)        { return c ^ ((c >> 5) << 3); }

// ---------------------------------------------------------------------------
// Kernel 1: h = emb[x]; LN1 stats (mu, rstd). One wave per token.
// ---------------------------------------------------------------------------
__global__ __launch_bounds__(256) void k_embed(const int* __restrict__ x,
                                               const float* __restrict__ emb,
                                               float* __restrict__ h,
                                               float* __restrict__ stats)
{
    int lane = threadIdx.x & 63;
    int wv   = threadIdx.x >> 6;
    int tok  = blockIdx.x * 4 + wv;
    int xi   = x[tok];
    float2 v = ((const float2*)(emb + xi * D))[lane];
    ((float2*)(h + (size_t)tok * D))[lane] = v;
    float s1 = wsum64(v.x + v.y);
    float s2 = wsum64(v.x * v.x + v.y * v.y);
    float mu  = s1 * (1.0f / D);
    float var = s2 * (1.0f / D) - mu * mu;
    if (lane == 0) {
        stats[tok * 2]     = mu;
        stats[tok * 2 + 1] = rsqrtf(var + EPS);
    }
}

// ---------------------------------------------------------------------------
// Kernel 1.5: gx = LN1(h) @ Wg + bias as a tiled GEMM.
// 32 tokens/block, 256 threads; whole Wg (64 KiB) staged once in LDS.
// ---------------------------------------------------------------------------
__global__ __launch_bounds__(256, 2) void k_gx(const float* __restrict__ Wg,    // (4,NH,DH,DH)
                                               const float* __restrict__ bias,  // (NH,4,DH)
                                               const float* __restrict__ lnw,   // (D)
                                               const float* __restrict__ h,     // (B*S, D)
                                               const float* __restrict__ stats, // (B*S, 2)
                                               float* __restrict__ gx)          // (B*NH*S, 128)
{
    __shared__ float xs[32 * 128];        // 16 KiB
    __shared__ float wl[4 * 32 * 128];    // 64 KiB  [n][k][gk'] swizzled

    int tid  = threadIdx.x;
    int lane = tid & 63;
    int wv   = tid >> 6;
    size_t tok0 = (size_t)blockIdx.x * 32;

    // ---- stage all Wg: wl[n][i][g*32+hh ^ sw] = Wg[g][n][hh][i] ----
    {
        int q = tid & 7;                   // float4 index along i
        #pragma unroll
        for (int it = 0; it < 16; ++it) {
            int row = it * 32 + (tid >> 3);        // 0..511 = (g*4+n)*32+hh
            int g  = row >> 7;
            int n  = (row >> 5) & 3;
            int hh = row & 31;
            float4 v = *(const float4*)(Wg + row * 32 + q * 4);
            int col = g * 32 + hh;
            int sw  = q << 2;
            float* dst = wl + n * 4096;
            dst[(q * 4 + 0) * 128 + (col ^ sw)] = v.x;
            dst[(q * 4 + 1) * 128 + (col ^ sw)] = v.y;
            dst[(q * 4 + 2) * 128 + (col ^ sw)] = v.z;
            dst[(q * 4 + 3) * 128 + (col ^ sw)] = v.w;
        }
    }
    // ---- stage xn (LN1 applied; stats precomputed) ----
    for (int i = 0; i < 8; ++i) {
        int t = wv * 8 + i;
        const float* hp = h + (tok0 + t) * D;
        float mu = stats[(tok0 + t) * 2];
        float rs = stats[(tok0 + t) * 2 + 1];
        float v1 = (hp[lane]      - mu) * rs * lnw[lane];
        float v2 = (hp[64 + lane] - mu) * rs * lnw[64 + lane];
        xs[t * 128 + xg(lane)]      = v1;
        xs[t * 128 + xg(lane + 64)] = v2;
    }
    __syncthreads();

    int nh   = lane >> 4;          // head
    int col0 = (lane & 15) * 8;    // 8 output cols within head
    int t0   = wv * 8;             // 8 tokens

    float acc[8][8];
    #pragma unroll
    for (int j = 0; j < 8; ++j)
        #pragma unroll
        for (int cc = 0; cc < 8; ++cc) acc[j][cc] = 0.f;

    const float* wbase = wl + nh * 4096;
    #pragma unroll 4
    for (int k = 0; k < 32; ++k) {
        int sw = (k >> 2) << 2;
        float4 w0 = *(const float4*)&wbase[k * 128 + (col0 ^ sw)];
        float4 w1 = *(const float4*)&wbase[k * 128 + ((col0 + 4) ^ sw)];
        int ac = (nh * 32 + k) ^ (nh << 3);
        #pragma unroll
        for (int j = 0; j < 8; ++j) {
            float a = xs[(t0 + j) * 128 + ac];
            acc[j][0] = fmaf(a, w0.x, acc[j][0]);
            acc[j][1] = fmaf(a, w0.y, acc[j][1]);
            acc[j][2] = fmaf(a, w0.z, acc[j][2]);
            acc[j][3] = fmaf(a, w0.w, acc[j][3]);
            acc[j][4] = fmaf(a, w1.x, acc[j][4]);
            acc[j][5] = fmaf(a, w1.y, acc[j][5]);
            acc[j][6] = fmaf(a, w1.z, acc[j][6]);
            acc[j][7] = fmaf(a, w1.w, acc[j][7]);
        }
    }

    float4 bb0 = *(const float4*)(bias + nh * 128 + col0);
    float4 bb1 = *(const float4*)(bias + nh * 128 + col0 + 4);
    #pragma unroll
    for (int j = 0; j < 8; ++j) {
        int gt = (int)tok0 + t0 + j;
        int bb = gt >> 6;
        int ss = gt & 63;
        float* op = gx + ((size_t)(bb * NH + nh) * S_LEN + ss) * 128 + col0;
        float4 o0v, o1v;
        o0v.x = acc[j][0] + bb0.x; o0v.y = acc[j][1] + bb0.y;
        o0v.z = acc[j][2] + bb0.z; o0v.w = acc[j][3] + bb0.w;
        o1v.x = acc[j][4] + bb1.x; o1v.y = acc[j][5] + bb1.y;
        o1v.z = acc[j][6] + bb1.z; o1v.w = acc[j][7] + bb1.w;
        *(float4*)op       = o0v;
        *(float4*)(op + 4) = o1v;
    }
}

// ---------------------------------------------------------------------------
// Kernel 2: sLSTM scan. R6-R8 post-mortem: the compiler pins itself at 48
// VGPRs and rematerializes the R loads inside the s-loop (global loads,
// latency-unhidden at 8 waves/CU -> 73 us). Structural fix: stage R in LDS
// once (16 KiB, ds_read_b128-friendly [chunk][lane][4] layout, conflict-
// free) — ds_read cannot be rematerialized into global traffic. gx/h loads
// get a 4-deep software pipeline to cover HBM latency.
// ---------------------------------------------------------------------------
__global__ __launch_bounds__(64, 1) void k_scan(const float* __restrict__ Rm,   // (NH,DH,4*DH)
                                                const float* __restrict__ gnw,  // (D)
                                                const float* __restrict__ gx,   // (B*NH*S, 128)
                                                float* __restrict__ h)          // (B*S, D) in/out
{
    __shared__ float WA[8][64][4];   // 8 KiB: RA chunks, lane-contiguous
    __shared__ float WB[8][64][4];   // 8 KiB: RB chunks

    int b    = blockIdx.x >> 2;
    int n    = blockIdx.x & 3;
    int lane = threadIdx.x;
    int e    = lane >> 1;
    int sub  = lane & 1;
    int colA = sub * DH + e;           // i (sub0) / f (sub1); +64 -> z/o

    // ---- stage R into LDS (once) ----
    #pragma unroll
    for (int cc = 0; cc < 8; ++cc) {
        float4 a, bv;
        #pragma unroll
        for (int j = 0; j < 4; ++j) {
            ((float*)&a)[j]  = Rm[(n * DH + cc * 4 + j) * 128 + colA];
            ((float*)&bv)[j] = Rm[(n * DH + cc * 4 + j) * 128 + 64 + colA];
        }
        *(float4*)WA[cc][lane] = a;
        *(float4*)WB[cc][lane] = bv;
    }
    float gw = gnw[n * DH + e];
    __syncthreads();

    float c = 0.f, nacc = 0.f, m = 0.f;
    float hu[DH];
    #pragma unroll
    for (int i = 0; i < DH; ++i) hu[i] = 0.f;

    float* hb = h + ((size_t)b * S_LEN) * D + n * DH;
    const float* gxp = gx + ((size_t)(b * NH + n) * S_LEN) * 128;

    // ---- 4-deep software pipeline on gx + residual-h loads ----
    float pGA[4], pGB[4], pHR[4];
    #pragma unroll
    for (int k = 0; k < 4; ++k) {
        pGA[k] = gxp[k * 128 + colA];
        pGB[k] = gxp[k * 128 + 64 + colA];
        pHR[k] = hb[k * D + e];
    }

    #pragma unroll 4
    for (int s = 0; s < S_LEN; ++s) {
        int sp = (s + 4 < S_LEN) ? s + 4 : S_LEN - 1;
        float nGA = gxp[sp * 128 + colA];
        float nGB = gxp[sp * 128 + 64 + colA];
        float nHR = hb[sp * D + e];

        float r0=0,r1=0,r2=0,r3=0,q0=0,q1=0,q2=0,q3=0;
        #pragma unroll
        for (int cc = 0; cc < 8; ++cc) {
            float4 wa = *(const float4*)WA[cc][lane];
            float4 wb = *(const float4*)WB[cc][lane];
            r0 = fmaf(hu[cc*4+0], wa.x, r0);
            r1 = fmaf(hu[cc*4+1], wa.y, r1);
            r2 = fmaf(hu[cc*4+2], wa.z, r2);
            r3 = fmaf(hu[cc*4+3], wa.w, r3);
            q0 = fmaf(hu[cc*4+0], wb.x, q0);
            q1 = fmaf(hu[cc*4+1], wb.y, q1);
            q2 = fmaf(hu[cc*4+2], wb.z, q2);
            q3 = fmaf(hu[cc*4+3], wb.w, q3);
        }
        float rawA = pGA[0] + ((r0 + r1) + (r2 + r3));
        float rawB = pGB[0] + ((q0 + q1) + (q2 + q3));

        float xA = dppf<0xB1>(rawA);   // quad_perm [1,0,3,2] = xor1
        float xB = dppf<0xB1>(rawB);
        float i_r = sub ? xA   : rawA;
        float f_r = sub ? rawA : xA;
        float z_r = sub ? xB   : rawB;
        float o_r = sub ? rawB : xB;

        // log_sigmoid(f) = min(f,0) - ln(1+exp(-|f|)) via hw exp/log2
        float lsf  = fminf(f_r, 0.f)
                   - 0.69314718055994531f * __log2f(1.0f + __expf(-fabsf(f_r)));
        float lfm  = m + lsf;
        float mnew = fmaxf(i_r, lfm);
        float ig   = __expf(i_r - mnew);
        float fg   = __expf(lfm - mnew);
        float t    = __expf(2.f * z_r);
        float tz   = 1.f - 2.f / (t + 1.f);   // tanh, stable both ends
        c    = fg * c + ig * tz;
        nacc = fg * nacc + ig;
        m    = mnew;
        float hv = c / (nacc * (1.f + __expf(-o_r)));   // sigmoid(o)*c/n

        // groupnorm over DH (each element appears twice -> /64)
        float s1 = wsum64(hv);
        float s2 = wsum64(hv * hv);
        float mu  = s1 * (1.f / 64.f);
        float var = s2 * (1.f / 64.f) - mu * mu;
        float hn  = (hv - mu) * rsqrtf(var + EPS) * gw;

        if (!sub) hb[s * D + e] = pHR[0] + hn;   // residual write (h_mid)

        #pragma unroll
        for (int i = 0; i < DH; ++i)
            hu[i] = __int_as_float(
                __builtin_amdgcn_readlane(__float_as_int(hv), 2 * i));

        pGA[0]=pGA[1]; pGA[1]=pGA[2]; pGA[2]=pGA[3]; pGA[3]=nGA;
        pGB[0]=pGB[1]; pGB[1]=pGB[2]; pGB[2]=pGB[3]; pGB[3]=nGB;
        pHR[0]=pHR[1]; pHR[1]=pHR[2]; pHR[2]=pHR[3]; pHR[3]=nHR;
    }
}

// ---------------------------------------------------------------------------
// Kernel 3: fused LN2 -> up GEMM -> GeLU -> down GEMM -> residual -> tail.
// 32 tokens/block, 256 threads, 40 KiB LDS.
// launch_bounds arg=2: empirically VGPR cap = 256/arg -> 128 (no spill);
// 128 VGPR + 40 KiB LDS still allows 4 blocks/CU.
// ---------------------------------------------------------------------------
template <int LAST>
__global__ __launch_bounds__(256, 2) void k_ff(float* __restrict__ h,
                                               const float* __restrict__ ln2w,
                                               const float* __restrict__ wup,    // (2D, D)
                                               const float* __restrict__ wdn,    // (D, D)
                                               float* __restrict__ stats_out,
                                               const float* __restrict__ lastw,
                                               const float* __restrict__ projw,
                                               const float* __restrict__ projb,
                                               float* __restrict__ out)
{
    __shared__ float xs[32 * 128];      // 16 KiB
    __shared__ float as_[32 * 64];      // 8 KiB
    __shared__ float wt[2 * 32 * 64];   // 16 KiB  [slot][k][o'] swizzled

    int tid  = threadIdx.x;
    int lane = tid & 63;
    int wv   = tid >> 6;
    size_t tok0 = (size_t)blockIdx.x * 32;

    // ---- phase 1: LN2 into xs ----
    for (int i = 0; i < 8; ++i) {
        int t = wv * 8 + i;
        const float* hp = h + (tok0 + t) * D;
        float v1 = hp[lane], v2 = hp[64 + lane];
        float s1 = wsum64(v1 + v2);
        float s2 = wsum64(v1 * v1 + v2 * v2);
        float mu = s1 * (1.0f / D);
        float rs = rsqrtf(s2 * (1.0f / D) - mu * mu + EPS);
        xs[t * D + xc3(t, lane)]      = (v1 - mu) * rs * ln2w[lane];
        xs[t * D + xc3(t, lane + 64)] = (v2 - mu) * rs * ln2w[64 + lane];
    }

    // staging constants: q = float4 idx along k, r0/r0+32 = output rows
    int q     = tid & 7;
    int r0    = tid >> 3;          // 0..31
    int goff0 = r0 * D + q * 4;
    int goff1 = (r0 + 32) * D + q * 4;
    int s0    = r0 ^ (q << 2);     // swizzled o-index for LDS store
    int kb    = q * 4;

    auto ffld = [&](int id, float4* pre) {
        int p = (id >= 6) ? 1 : 0;
        int j = id - p * 6;
        const float* b0;
        const float* b1;
        if (j < 4) { b0 = wup + (p * 64) * D + j * 32;
                     b1 = wup + (128 + p * 64) * D + j * 32; }
        else       { int jj = j - 4;
                     b0 = wdn + p * 64 + jj * 32;
                     b1 = wdn + 64 * D + p * 64 + jj * 32; }
        pre[0] = *(const float4*)(b0 + goff0);
        pre[1] = *(const float4*)(b0 + goff1);
        pre[2] = *(const float4*)(b1 + goff0);
        pre[3] = *(const float4*)(b1 + goff1);
    };
    auto fst = [&](const float4* pre) {
        #pragma unroll
        for (int cc = 0; cc < 4; ++cc) {
            const float* p0 = (const float*)&pre[0];
            const float* p1 = (const float*)&pre[1];
            const float* p2 = (const float*)&pre[2];
            const float* p3 = (const float*)&pre[3];
            wt[(kb + cc) * 64 + s0]           = p0[cc];
            wt[(kb + cc) * 64 + s0 + 32]      = p1[cc];
            wt[2048 + (kb + cc) * 64 + s0]      = p2[cc];
            wt[2048 + (kb + cc) * 64 + s0 + 32] = p3[cc];
        }
    };

    int ti = tid >> 4;    // 0..15
    int oi = tid & 15;    // 0..15
    int t0 = ti * 2;
    int o0 = oi * 4;

    float accd[2][2][4];
    #pragma unroll
    for (int a1 = 0; a1 < 2; ++a1)
        #pragma unroll
        for (int j = 0; j < 2; ++j)
            #pragma unroll
            for (int cc = 0; cc < 4; ++cc) accd[a1][j][cc] = 0.f;

    float4 pre[4];
    ffld(0, pre);
    int id = 1;

    #pragma unroll
    for (int p = 0; p < 2; ++p) {
        float accg[2][4], accv[2][4];
        #pragma unroll
        for (int j = 0; j < 2; ++j)
            #pragma unroll
            for (int cc = 0; cc < 4; ++cc) { accg[j][cc] = 0.f; accv[j][cc] = 0.f; }

        // ---- UP: 4 chunks of 32 k ----
        for (int c4 = 0; c4 < 4; ++c4) {
            __syncthreads();
            fst(pre);
            if (id < 12) ffld(id, pre);
            ++id;
            __syncthreads();
            int kc = c4 * 32;
            #pragma unroll
            for (int k4 = 0; k4 < 8; ++k4) {
                float4 a0 = *(const float4*)&xs[t0 * D + xc3(t0, kc + k4 * 4)];
                float4 a1v = *(const float4*)&xs[(t0 + 1) * D + xc3(t0 + 1, kc + k4 * 4)];
                int ws = k4 << 2;
                #pragma unroll
                for (int i = 0; i < 4; ++i) {
                    int k = k4 * 4 + i;
                    float4 bg = *(const float4*)&wt[k * 64 + (o0 ^ ws)];
                    float4 bv = *(const float4*)&wt[2048 + k * 64 + (o0 ^ ws)];
                    float ax0 = ((const float*)&a0)[i];
                    float ax1 = ((const float*)&a1v)[i];
                    accg[0][0] = fmaf(ax0, bg.x, accg[0][0]);
                    accg[0][1] = fmaf(ax0, bg.y, accg[0][1]);
                    accg[0][2] = fmaf(ax0, bg.z, accg[0][2]);
                    accg[0][3] = fmaf(ax0, bg.w, accg[0][3]);
                    accg[1][0] = fmaf(ax1, bg.x, accg[1][0]);
                    accg[1][1] = fmaf(ax1, bg.y, accg[1][1]);
                    accg[1][2] = fmaf(ax1, bg.z, accg[1][2]);
                    accg[1][3] = fmaf(ax1, bg.w, accg[1][3]);
                    accv[0][0] = fmaf(ax0, bv.x, accv[0][0]);
                    accv[0][1] = fmaf(ax0, bv.y, accv[0][1]);
                    accv[0][2] = fmaf(ax0, bv.z, accv[0][2]);
                    accv[0][3] = fmaf(ax0, bv.w, accv[0][3]);
                    accv[1][0] = fmaf(ax1, bv.x, accv[1][0]);
                    accv[1][1] = fmaf(ax1, bv.y, accv[1][1]);
                    accv[1][2] = fmaf(ax1, bv.z, accv[1][2]);
                    accv[1][3] = fmaf(ax1, bv.w, accv[1][3]);
                }
            }
        }
        // act = gelu_exact(gate) * val -> as_
        #pragma unroll
        for (int j = 0; j < 2; ++j) {
            int t = t0 + j;
            float4 av;
            float* ap = (float*)&av;
            #pragma unroll
            for (int cc = 0; cc < 4; ++cc) {
                float g = accg[j][cc];
                float u = accv[j][cc];
                ap[cc] = 0.5f * g * (1.0f + erff(g * 0.70710678118654752f)) * u;
            }
            *(float4*)&as_[t * 64 + xa(t, o0)] = av;
        }
        // ---- DOWN: 2 chunks of 32 k ----
        for (int c2 = 0; c2 < 2; ++c2) {
            __syncthreads();
            fst(pre);
            if (id < 12) ffld(id, pre);
            ++id;
            __syncthreads();
            int kc = c2 * 32;
            #pragma unroll
            for (int k4 = 0; k4 < 8; ++k4) {
                float4 a0 = *(const float4*)&as_[t0 * 64 + xa(t0, kc + k4 * 4)];
                float4 a1v = *(const float4*)&as_[(t0 + 1) * 64 + xa(t0 + 1, kc + k4 * 4)];
                int ws = k4 << 2;
                #pragma unroll
                for (int i = 0; i < 4; ++i) {
                    int k = k4 * 4 + i;
                    float4 b0v = *(const float4*)&wt[k * 64 + (o0 ^ ws)];
                    float4 b1v = *(const float4*)&wt[2048 + k * 64 + (o0 ^ ws)];
                    float ax0 = ((const float*)&a0)[i];
                    float ax1 = ((const float*)&a1v)[i];
                    accd[0][0][0] = fmaf(ax0, b0v.x, accd[0][0][0]);
                    accd[0][0][1] = fmaf(ax0, b0v.y, accd[0][0][1]);
                    accd[0][0][2] = fmaf(ax0, b0v.z, accd[0][0][2]);
                    accd[0][0][3] = fmaf(ax0, b0v.w, accd[0][0][3]);
                    accd[0][1][0] = fmaf(ax1, b0v.x, accd[0][1][0]);
                    accd[0][1][1] = fmaf(ax1, b0v.y, accd[0][1][1]);
                    accd[0][1][2] = fmaf(ax1, b0v.z, accd[0][1][2]);
                    accd[0][1][3] = fmaf(ax1, b0v.w, accd[0][1][3]);
                    accd[1][0][0] = fmaf(ax0, b1v.x, accd[1][0][0]);
                    accd[1][0][1] = fmaf(ax0, b1v.y, accd[1][0][1]);
                    accd[1][0][2] = fmaf(ax0, b1v.z, accd[1][0][2]);
                    accd[1][0][3] = fmaf(ax0, b1v.w, accd[1][0][3]);
                    accd[1][1][0] = fmaf(ax1, b1v.x, accd[1][1][0]);
                    accd[1][1][1] = fmaf(ax1, b1v.y, accd[1][1][1]);
                    accd[1][1][2] = fmaf(ax1, b1v.z, accd[1][1][2]);
                    accd[1][1][3] = fmaf(ax1, b1v.w, accd[1][1][3]);
                }
            }
        }
    }

    // ---- epilogue: residual add, stash hnew in xs ----
    #pragma unroll
    for (int j = 0; j < 2; ++j) {
        int t = t0 + j;
        size_t tok = tok0 + t;
        #pragma unroll
        for (int a1 = 0; a1 < 2; ++a1) {
            int cb = a1 * 64 + o0;
            float4 hres = *(const float4*)(h + tok * D + cb);
            float4 hn;
            hn.x = hres.x + accd[a1][j][0];
            hn.y = hres.y + accd[a1][j][1];
            hn.z = hres.z + accd[a1][j][2];
            hn.w = hres.w + accd[a1][j][3];
            if (!LAST) *(float4*)(h + tok * D + cb) = hn;
            *(float4*)&xs[t * D + xc3(t, cb)] = hn;
        }
    }
    __syncthreads();

    // ---- final per-token phase ----
    if (!LAST) {
        for (int i = 0; i < 8; ++i) {
            int t = wv * 8 + i;
            float v1 = xs[t * D + xc3(t, lane)];
            float v2 = xs[t * D + xc3(t, lane + 64)];
            float s1 = wsum64(v1 + v2);
            float s2 = wsum64(v1 * v1 + v2 * v2);
            float mu = s1 * (1.0f / D);
            float rs = rsqrtf(s2 * (1.0f / D) - mu * mu + EPS);
            if (lane == 0) {
                stats_out[(tok0 + t) * 2]     = mu;
                stats_out[(tok0 + t) * 2 + 1] = rs;
            }
        }
    } else {
        float pw1[VOCAB], pw2[VOCAB], pb[VOCAB];
        #pragma unroll
        for (int v = 0; v < VOCAB; ++v) {
            pw1[v] = projw[v * D + lane];
            pw2[v] = projw[v * D + 64 + lane];
            pb[v]  = projb[v];
        }
        for (int i = 0; i < 8; ++i) {
            int t = wv * 8 + i;
            float v1 = xs[t * D + xc3(t, lane)];
            float v2 = xs[t * D + xc3(t, lane + 64)];
            float s1 = wsum64(v1 + v2);
            float s2 = wsum64(v1 * v1 + v2 * v2);
            float mu = s1 * (1.0f / D);
            float rs = rsqrtf(s2 * (1.0f / D) - mu * mu + EPS);
            float x1 = (v1 - mu) * rs * lastw[lane];
            float x2 = (v2 - mu) * rs * lastw[64 + lane];
            #pragma unroll
            for (int v = 0; v < VOCAB; ++v) {
                float pp = wsum64(fmaf(x1, pw1[v], x2 * pw2[v]));
                if (lane == 0) out[(tok0 + t) * VOCAB + v] = pp + pb[v];
            }
        }
    }
}

// ---------------------------------------------------------------------------
extern "C" void kernel_launch(void* const* d_in, const int* in_sizes, int n_in,
                              void* d_out, int out_size, void* d_ws, size_t ws_size,
                              hipStream_t stream)
{
    const int*   x     = (const int*)  d_in[0];
    const float* emb   = (const float*)d_in[1];
    const float* ln1   = (const float*)d_in[2];
    const float* Wg    = (const float*)d_in[3];
    const float* Rm    = (const float*)d_in[4];
    const float* bias  = (const float*)d_in[5];
    const float* gnw   = (const float*)d_in[6];
    const float* ln2   = (const float*)d_in[7];
    const float* wup   = (const float*)d_in[8];
    const float* wdn   = (const float*)d_in[9];
    const float* postw = (const float*)d_in[10];
    const float* projw = (const float*)d_in[11];
    const float* projb = (const float*)d_in[12];
    float* out   = (float*)d_out;
    float* hbuf  = (float*)d_ws;                       // (B*S, D)
    float* stats = hbuf + (size_t)NTOK * D;            // (B*S, 2)
    float* gxbuf = stats + (size_t)NTOK * 2;           // (B*NH*S, 128)

    k_embed<<<NTOK / 4, 256, 0, stream>>>(x, emb, hbuf, stats);

    for (int bi = 0; bi < NB; ++bi) {
        k_gx<<<NTOK / 32, 256, 0, stream>>>(Wg + bi * 4 * NH * DH * DH,
                                            bias + bi * NH * 4 * DH,
                                            ln1 + bi * D,
                                            hbuf, stats, gxbuf);
        k_scan<<<B_SZ * NH, 64, 0, stream>>>(Rm + bi * NH * DH * 4 * DH,
                                             gnw + bi * D,
                                             gxbuf, hbuf);
        if (bi == 0)
            k_ff<0><<<NTOK / 32, 256, 0, stream>>>(hbuf, ln2 + bi * D,
                                                   wup + bi * 2 * D * D,
                                                   wdn + bi * D * D,
                                                   stats, nullptr, nullptr,
                                                   nullptr, nullptr);
        else
            k_ff<1><<<NTOK / 32, 256, 0, stream>>>(hbuf, ln2 + bi * D,
                                                   wup + bi * 2 * D * D,
                                                   wdn + bi * D * D,
                                                   nullptr, postw, projw,
                                                   projb, out);
    }
}